// Round 4
// baseline (1096.637 us; speedup 1.0000x reference)
//
#include <hip/hip_runtime.h>
#include <math.h>

// ---------------------------------------------------------------------------
// 2-layer GCN, commuted form:  layer(X) = act((M·X)@W + b),  M = D^-1/2(A+I)D^-1/2
// Gather (M·X) is edge-parallel into LDS via ds_add_f32 (load-balanced, high MLP),
// fused with the GEMM. CSR+edge-coef records built per call.
// ---------------------------------------------------------------------------

#define SCAN_CHUNK 2048
#define RPB 32                      // node rows per block (both layers)

__global__ __launch_bounds__(256) void k_count(const int* __restrict__ dst, int* cnt,
                                               int* __restrict__ epos, int e) {
    int i = blockIdx.x * blockDim.x + threadIdx.x;
    if (i < e) epos[i] = atomicAdd(&cnt[dst[i]], 1);
}

__global__ __launch_bounds__(256) void k_blksum(const int* __restrict__ cnt, int* __restrict__ blkSum, int n) {
    __shared__ int part[256];
    const int t = threadIdx.x;
    const int base = blockIdx.x * SCAN_CHUNK + t * 8;
    int s = 0;
#pragma unroll
    for (int q = 0; q < 8; ++q) {
        int i = base + q;
        s += (i < n) ? cnt[i] : 0;
    }
    part[t] = s;
    __syncthreads();
    for (int off = 128; off > 0; off >>= 1) {
        if (t < off) part[t] += part[t + off];
        __syncthreads();
    }
    if (t == 0) blkSum[blockIdx.x] = part[0];
}

__global__ __launch_bounds__(256) void k_scanblk(const int* __restrict__ blkSum, int* __restrict__ blkoff,
                                                 int* __restrict__ rowptr, int nb, int n) {
    __shared__ int part[256];
    const int t = threadIdx.x;
    int v = (t < nb) ? blkSum[t] : 0;
    part[t] = v;
    __syncthreads();
    for (int off = 1; off < 256; off <<= 1) {
        int u = (t >= off) ? part[t - off] : 0;
        __syncthreads();
        part[t] += u;
        __syncthreads();
    }
    if (t < nb) blkoff[t] = part[t] - v;
    if (t == 255) rowptr[n] = part[255];
}

__global__ __launch_bounds__(256) void k_apply(const int* __restrict__ cnt, const int* __restrict__ blkoff,
                                               int* __restrict__ rowptr, float* __restrict__ dinv, int n) {
    __shared__ int part[256];
    const int t = threadIdx.x;
    const int base = blockIdx.x * SCAN_CHUNK + t * 8;
    int v[8];
    int s = 0;
#pragma unroll
    for (int q = 0; q < 8; ++q) {
        int i = base + q;
        v[q] = (i < n) ? cnt[i] : 0;
        s += v[q];
    }
    part[t] = s;
    __syncthreads();
    for (int off = 1; off < 256; off <<= 1) {
        int u = (t >= off) ? part[t - off] : 0;
        __syncthreads();
        part[t] += u;
        __syncthreads();
    }
    int run = part[t] - s + blkoff[blockIdx.x];
#pragma unroll
    for (int q = 0; q < 8; ++q) {
        int i = base + q;
        if (i < n) {
            rowptr[i] = run;
            dinv[i]   = rsqrtf((float)(v[q] + 1));   // +1 self-loop
            run += v[q];
        }
    }
}

// Build packed edge records: (src | (dstRowInBlock << 17), dinv[s]*dinv[d])
__global__ __launch_bounds__(256) void k_fill(const int* __restrict__ src, const int* __restrict__ dst,
                                              const int* __restrict__ rowptr, const int* __restrict__ epos,
                                              const float* __restrict__ dinv,
                                              int2* __restrict__ erec, int e) {
    int i = blockIdx.x * blockDim.x + threadIdx.x;
    if (i < e) {
        int d = dst[i];
        int s = src[i];
        float c = dinv[s] * dinv[d];
        erec[rowptr[d] + epos[i]] = make_int2(s | ((d & (RPB - 1)) << 17), __float_as_int(c));
    }
}

// ---------------------------------------------------------------------------
// Fused layer: Out[r] = act((M·X)[r] @ W + bias), RPB=32 rows per block.
// Phase 1: self-loops -> sM;  Phase 2: edge-parallel ds_add_f32 accumulate;
// Phase 3: GEMM vs W in 32-k LDS chunks, TR-row x 4-col register tiles.
// ---------------------------------------------------------------------------
template <int COLS, int TR, bool RELU>
__global__ __launch_bounds__(256) void fused_layer(const float* __restrict__ X,
                                                   const float* __restrict__ W,
                                                   const float* __restrict__ bias,
                                                   const int* __restrict__ rowptr,
                                                   const int2* __restrict__ erec,
                                                   const float* __restrict__ dinv,
                                                   float* __restrict__ Out, int n) {
    constexpr int PAD = RPB + 4;                 // 36 floats = 144 B (16B multiple)
    __shared__ __align__(16) float sM[128][PAD];
    __shared__ __align__(16) float sW[32][COLS];

    const int t    = threadIdx.x;
    const int row0 = blockIdx.x * RPB;
    const int i    = t & 7;                      // lane-in-group
    const int g    = t >> 3;                     // group 0..31

    // ---- phase 1: self-loop init  sM[k][g] = dinv[d]^2 * X[d][k] ----
    {
        const int d = row0 + g;
        if (d < n) {
            const float wd = dinv[d];
            const float c  = wd * wd;
            const float* Xd = X + (size_t)d * 128;
#pragma unroll
            for (int j = 0; j < 16; ++j) {
                int k = i + 8 * j;               // bank (4i+g)%32: conflict-free-ish
                sM[k][g] = c * Xd[k];
            }
        } else {
#pragma unroll
            for (int j = 0; j < 16; ++j) sM[i + 8 * j][g] = 0.f;
        }
    }
    __syncthreads();

    // ---- phase 2: edge-parallel accumulate (one edge per 8-lane group) ----
    {
        const int e0 = rowptr[row0];
        const int e1 = rowptr[min(row0 + RPB, n)];
        int e = e0 + g;
        int2 rec = (e < e1) ? erec[e] : make_int2(0, 0);
        while (e < e1) {
            const int2 cur = rec;
            const int  en  = e + 32;
            if (en < e1) rec = erec[en];          // prefetch next record
            const int   s = cur.x & 0x1FFFF;
            const int   r = cur.x >> 17;
            const float c = __int_as_float(cur.y);
            const float* Xs = X + (size_t)s * 128;
            float v[16];
#pragma unroll
            for (int j = 0; j < 16; ++j) v[j] = Xs[i + 8 * j];   // 16 independent loads
#pragma unroll
            for (int j = 0; j < 16; ++j)
                atomicAdd(&sM[i + 8 * j][r], c * v[j]);          // ds_add_f32, bank (4i+r)%32
            e = en;
        }
    }

    // ---- phase 3: GEMM  acc[TR][4] per thread ----
    const int tcx = t % (COLS / 4);
    const int tcy = t / (COLS / 4);
    float acc[TR][4] = {};

    for (int kc = 0; kc < 128; kc += 32) {
        __syncthreads();                          // 1st: sM atomics done; later: sW reuse
        const float4* Wf4 = (const float4*)(W + (size_t)kc * COLS);
        float4* sWf4 = (float4*)&sW[0][0];
        for (int f = t; f < 32 * COLS / 4; f += 256) sWf4[f] = Wf4[f];
        __syncthreads();
#pragma unroll 8
        for (int k = 0; k < 32; ++k) {
            float av[TR];
            if constexpr (TR == 4) {
                float4 a = *(const float4*)&sM[kc + k][tcy * 4];
                av[0] = a.x; av[1] = a.y; av[2] = a.z; av[3] = a.w;
            } else {
                float2 a = *(const float2*)&sM[kc + k][tcy * 2];
                av[0] = a.x; av[1] = a.y;
            }
            float4 b = *(const float4*)&sW[k][tcx * 4];
            float bv[4] = {b.x, b.y, b.z, b.w};
#pragma unroll
            for (int ii = 0; ii < TR; ++ii)
#pragma unroll
                for (int jj = 0; jj < 4; ++jj) acc[ii][jj] += av[ii] * bv[jj];
        }
    }

    // ---- epilogue ----
    float4 bv4 = *(const float4*)&bias[tcx * 4];
    float bb[4] = {bv4.x, bv4.y, bv4.z, bv4.w};
#pragma unroll
    for (int ii = 0; ii < TR; ++ii) {
        int r = row0 + tcy * TR + ii;
        if (r < n) {
            float o[4];
#pragma unroll
            for (int jj = 0; jj < 4; ++jj) {
                o[jj] = acc[ii][jj] + bb[jj];
                if (RELU) o[jj] = fmaxf(o[jj], 0.f);
            }
            *(float4*)&Out[(size_t)r * COLS + tcx * 4] = make_float4(o[0], o[1], o[2], o[3]);
        }
    }
}

// ---------------------------------------------------------------------------

extern "C" void kernel_launch(void* const* d_in, const int* in_sizes, int n_in,
                              void* d_out, int out_size, void* d_ws, size_t ws_size,
                              hipStream_t stream) {
    const float* x  = (const float*)d_in[0];
    const int*   ei = (const int*)d_in[1];
    const float* W1 = (const float*)d_in[2];
    const float* b1 = (const float*)d_in[3];
    const float* W2 = (const float*)d_in[4];
    const float* b2 = (const float*)d_in[5];
    float* out = (float*)d_out;

    const int N = in_sizes[0] / 128;
    const int E = in_sizes[1] / 2;
    const int* src = ei;
    const int* dst = ei + E;
    const int NB = (N + SCAN_CHUNK - 1) / SCAN_CHUNK;   // 25 (<=256 required)

    // workspace carve (256B aligned)
    size_t off = 0;
    char* base = (char*)d_ws;
    auto carve = [&](size_t bytes) -> void* {
        void* p = base + off;
        off += (bytes + 255) & ~(size_t)255;
        return p;
    };
    int*   cnt    = (int*)carve((size_t)N * 4);
    int*   rowptr = (int*)carve((size_t)(N + 1) * 4);
    float* dinv   = (float*)carve((size_t)N * 4);
    int2*  erec   = (int2*)carve((size_t)E * 8);
    int*   blkSum = (int*)carve((size_t)NB * 4);
    int*   blkoff = (int*)carve((size_t)NB * 4);
    float* a1     = (float*)carve((size_t)N * 128 * 4);
    int*   epos   = (int*)a1;   // alias: epos dead before a1 is first written

    if (off > ws_size) return;  // diagnostic guard

    // 1) CSR + packed edge records
    hipMemsetAsync(cnt, 0, (size_t)N * 4, stream);
    k_count  <<<(E + 255) / 256, 256, 0, stream>>>(dst, cnt, epos, E);
    k_blksum <<<NB, 256, 0, stream>>>(cnt, blkSum, N);
    k_scanblk<<<1, 256, 0, stream>>>(blkSum, blkoff, rowptr, NB, N);
    k_apply  <<<NB, 256, 0, stream>>>(cnt, blkoff, rowptr, dinv, N);
    k_fill   <<<(E + 255) / 256, 256, 0, stream>>>(src, dst, rowptr, epos, dinv, erec, E);

    const int nblk = (N + RPB - 1) / RPB;
    // 2) layer 1: a1 = relu((M x) @ W1 + b1)
    fused_layer<128, 4, true><<<nblk, 256, 0, stream>>>(x, W1, b1, rowptr, erec, dinv, a1, N);
    // 3) layer 2: out = (M a1) @ W2 + b2
    fused_layer<64, 2, false><<<nblk, 256, 0, stream>>>(a1, W2, b2, rowptr, erec, dinv, out, N);
}

// Round 5
// 264.486 us; speedup vs baseline: 4.1463x; 4.1463x over previous
//
#include <hip/hip_runtime.h>
#include <math.h>

// ---------------------------------------------------------------------------
// 2-layer GCN, commuted form:  layer(X) = act((M·X)@W + b),  M = D^-1/2(A+I)D^-1/2
// Gather = per-row register accumulation (8 lanes/row, float4 loads), 2-deep
// edge pipeline with pre-packed (src, coef) records; fused into the GEMM.
// CSR built per call: histogram -> single-kernel chained scan -> scatter.
// ---------------------------------------------------------------------------

#define SCAN_CHUNK 8192
#define RPB 32                      // node rows per fused block

__global__ __launch_bounds__(256) void k_count(const int* __restrict__ dst, int* cnt,
                                               int* __restrict__ epos, int e) {
    int i = blockIdx.x * blockDim.x + threadIdx.x;
    if (i < e) epos[i] = atomicAdd(&cnt[dst[i]], 1);
}

// Single-kernel chained exclusive scan (nb blocks, 8192 elems each).
// Also emits dinv = rsqrt(deg+1). Blocks hand off inclusive prefixes via
// agent-scope (flg, incl) pairs; nb=7 << 256 CUs so all blocks co-resident.
__global__ __launch_bounds__(256) void k_scan1(const int* __restrict__ cnt,
                                               int* __restrict__ rowptr, float* __restrict__ dinv,
                                               int* __restrict__ flg, int* __restrict__ incl,
                                               int n, int nb) {
    __shared__ int part[256];
    __shared__ int sPrev;
    const int t   = threadIdx.x;
    const int blk = blockIdx.x;
    const int base = blk * SCAN_CHUNK + t * 32;
    int v[32];
    int s = 0;
#pragma unroll
    for (int q = 0; q < 32; ++q) {
        int i = base + q;
        v[q] = (i < n) ? cnt[i] : 0;
        s += v[q];
    }
    part[t] = s;
    __syncthreads();
    for (int off = 1; off < 256; off <<= 1) {
        int u = (t >= off) ? part[t - off] : 0;
        __syncthreads();
        part[t] += u;
        __syncthreads();
    }
    if (t == 0) {
        int prev = 0;
        if (blk > 0) {
            while (__hip_atomic_load(&flg[blk - 1], __ATOMIC_ACQUIRE, __HIP_MEMORY_SCOPE_AGENT) == 0) {}
            prev = __hip_atomic_load(&incl[blk - 1], __ATOMIC_RELAXED, __HIP_MEMORY_SCOPE_AGENT);
        }
        const int total = part[255];
        __hip_atomic_store(&incl[blk], prev + total, __ATOMIC_RELAXED, __HIP_MEMORY_SCOPE_AGENT);
        __hip_atomic_store(&flg[blk], 1, __ATOMIC_RELEASE, __HIP_MEMORY_SCOPE_AGENT);
        if (blk == nb - 1) rowptr[n] = prev + total;
        sPrev = prev;
    }
    __syncthreads();
    int run = sPrev + part[t] - s;
#pragma unroll
    for (int q = 0; q < 32; ++q) {
        int i = base + q;
        if (i < n) {
            rowptr[i] = run;
            dinv[i]   = rsqrtf((float)(v[q] + 1));   // +1 self-loop
            run += v[q];
        }
    }
}

// Packed edge records sorted by dst: (src, dinv[src]*dinv[dst])
__global__ __launch_bounds__(256) void k_fill(const int* __restrict__ src, const int* __restrict__ dst,
                                              const int* __restrict__ rowptr, const int* __restrict__ epos,
                                              const float* __restrict__ dinv,
                                              int2* __restrict__ erec, int e) {
    int i = blockIdx.x * blockDim.x + threadIdx.x;
    if (i < e) {
        int d = dst[i];
        int s = src[i];
        erec[rowptr[d] + epos[i]] = make_int2(s, __float_as_int(dinv[s] * dinv[d]));
    }
}

// ---------------------------------------------------------------------------
// Fused layer: Out[r] = act((M·X)[r] @ W + bias), RPB=32 rows per 256-thr block.
// Gather: 8 lanes/row, 16 feats/lane (4x float4), 2 edges in flight.
// GEMM: W staged in 32-k LDS chunks; TRx4 register tile per thread.
// ---------------------------------------------------------------------------
template <int COLS, int TR, bool RELU>
__global__ __launch_bounds__(256, 4) void fused_layer(const float* __restrict__ X,
                                                      const float* __restrict__ W,
                                                      const float* __restrict__ bias,
                                                      const int* __restrict__ rowptr,
                                                      const int2* __restrict__ erec,
                                                      const float* __restrict__ dinv,
                                                      float* __restrict__ Out, int n) {
    constexpr int PAD = RPB + 4;                 // 36 floats (16B multiple)
    __shared__ __align__(16) float sM[128][PAD];
    __shared__ __align__(16) float sW[32][COLS];

    const int t    = threadIdx.x;
    const int row0 = blockIdx.x * RPB;
    const int r    = t >> 3;                     // row-in-block 0..31
    const int seg  = (t & 7) * 16;               // feature segment base

    // ---- gather: ga[16] = dinv_d^2 * X[d] + sum_e coef_e * X[src_e] ----
    {
        const int d = row0 + r;
        if (d < n) {
            const float wd = dinv[d];
            const float cc = wd * wd;
            float ga[16];
            const float4* Xd = (const float4*)&X[(size_t)d * 128 + seg];
#pragma unroll
            for (int q = 0; q < 4; ++q) {
                float4 x4 = Xd[q];
                ga[q * 4 + 0] = cc * x4.x; ga[q * 4 + 1] = cc * x4.y;
                ga[q * 4 + 2] = cc * x4.z; ga[q * 4 + 3] = cc * x4.w;
            }
            const int beg = rowptr[d], end = rowptr[d + 1];
            int j = beg;
            int2 r0, r1;
            if (j     < end) r0 = erec[j];
            if (j + 1 < end) r1 = erec[j + 1];
            while (j < end) {
                const int2 c0 = r0;
                const int2 c1 = r1;
                const bool has1 = (j + 1 < end);
                if (j + 2 < end) r0 = erec[j + 2];   // prefetch next pair
                if (j + 3 < end) r1 = erec[j + 3];
                const float4* P0 = (const float4*)&X[(size_t)c0.x * 128 + seg];
                float4 a0 = P0[0], a1 = P0[1], a2 = P0[2], a3 = P0[3];
                const float w0 = __int_as_float(c0.y);
                if (has1) {
                    const float4* P1 = (const float4*)&X[(size_t)c1.x * 128 + seg];
                    float4 b0 = P1[0], b1 = P1[1], b2 = P1[2], b3 = P1[3];
                    const float w1 = __int_as_float(c1.y);
                    ga[0]  += w0 * a0.x + w1 * b0.x;  ga[1]  += w0 * a0.y + w1 * b0.y;
                    ga[2]  += w0 * a0.z + w1 * b0.z;  ga[3]  += w0 * a0.w + w1 * b0.w;
                    ga[4]  += w0 * a1.x + w1 * b1.x;  ga[5]  += w0 * a1.y + w1 * b1.y;
                    ga[6]  += w0 * a1.z + w1 * b1.z;  ga[7]  += w0 * a1.w + w1 * b1.w;
                    ga[8]  += w0 * a2.x + w1 * b2.x;  ga[9]  += w0 * a2.y + w1 * b2.y;
                    ga[10] += w0 * a2.z + w1 * b2.z;  ga[11] += w0 * a2.w + w1 * b2.w;
                    ga[12] += w0 * a3.x + w1 * b3.x;  ga[13] += w0 * a3.y + w1 * b3.y;
                    ga[14] += w0 * a3.z + w1 * b3.z;  ga[15] += w0 * a3.w + w1 * b3.w;
                } else {
                    ga[0]  += w0 * a0.x;  ga[1]  += w0 * a0.y;
                    ga[2]  += w0 * a0.z;  ga[3]  += w0 * a0.w;
                    ga[4]  += w0 * a1.x;  ga[5]  += w0 * a1.y;
                    ga[6]  += w0 * a1.z;  ga[7]  += w0 * a1.w;
                    ga[8]  += w0 * a2.x;  ga[9]  += w0 * a2.y;
                    ga[10] += w0 * a2.z;  ga[11] += w0 * a2.w;
                    ga[12] += w0 * a3.x;  ga[13] += w0 * a3.y;
                    ga[14] += w0 * a3.z;  ga[15] += w0 * a3.w;
                }
                j += 2;
            }
#pragma unroll
            for (int q = 0; q < 16; ++q) sM[seg + q][r] = ga[q];
        } else {
#pragma unroll
            for (int q = 0; q < 16; ++q) sM[seg + q][r] = 0.f;
        }
    }

    // ---- GEMM: acc[TR][4] per thread ----
    const int tcx = t % (COLS / 4);
    const int tcy = t / (COLS / 4);
    float acc[TR][4] = {};

    for (int kc = 0; kc < 128; kc += 32) {
        __syncthreads();                          // 1st: sM ready; later: sW reuse safe
        const float4* Wf4 = (const float4*)(W + (size_t)kc * COLS);
        float4* sWf4 = (float4*)&sW[0][0];
        for (int f = t; f < 32 * COLS / 4; f += 256) sWf4[f] = Wf4[f];
        __syncthreads();
#pragma unroll 8
        for (int k = 0; k < 32; ++k) {
            float av[TR];
            if constexpr (TR == 4) {
                float4 a = *(const float4*)&sM[kc + k][tcy * 4];
                av[0] = a.x; av[1] = a.y; av[2] = a.z; av[3] = a.w;
            } else {
                float2 a = *(const float2*)&sM[kc + k][tcy * 2];
                av[0] = a.x; av[1] = a.y;
            }
            float4 b = *(const float4*)&sW[k][tcx * 4];
            float bv[4] = {b.x, b.y, b.z, b.w};
#pragma unroll
            for (int ii = 0; ii < TR; ++ii)
#pragma unroll
                for (int jj = 0; jj < 4; ++jj) acc[ii][jj] += av[ii] * bv[jj];
        }
    }

    // ---- epilogue ----
    float4 bv4 = *(const float4*)&bias[tcx * 4];
    float bb[4] = {bv4.x, bv4.y, bv4.z, bv4.w};
#pragma unroll
    for (int ii = 0; ii < TR; ++ii) {
        int rr = row0 + tcy * TR + ii;
        if (rr < n) {
            float o[4];
#pragma unroll
            for (int jj = 0; jj < 4; ++jj) {
                o[jj] = acc[ii][jj] + bb[jj];
                if (RELU) o[jj] = fmaxf(o[jj], 0.f);
            }
            *(float4*)&Out[(size_t)rr * COLS + tcx * 4] = make_float4(o[0], o[1], o[2], o[3]);
        }
    }
}

// ---------------------------------------------------------------------------

extern "C" void kernel_launch(void* const* d_in, const int* in_sizes, int n_in,
                              void* d_out, int out_size, void* d_ws, size_t ws_size,
                              hipStream_t stream) {
    const float* x  = (const float*)d_in[0];
    const int*   ei = (const int*)d_in[1];
    const float* W1 = (const float*)d_in[2];
    const float* b1 = (const float*)d_in[3];
    const float* W2 = (const float*)d_in[4];
    const float* b2 = (const float*)d_in[5];
    float* out = (float*)d_out;

    const int N = in_sizes[0] / 128;
    const int E = in_sizes[1] / 2;
    const int* src = ei;
    const int* dst = ei + E;
    const int NB = (N + SCAN_CHUNK - 1) / SCAN_CHUNK;   // 7 for N=50000

    // workspace carve (256B aligned)
    size_t off = 0;
    char* base = (char*)d_ws;
    auto carve = [&](size_t bytes) -> void* {
        void* p = base + off;
        off += (bytes + 255) & ~(size_t)255;
        return p;
    };
    int*   cnt    = (int*)carve((size_t)N * 4);         // | zeroed as one span
    int*   flg    = (int*)carve((size_t)NB * 4);        // |
    int*   incl   = (int*)carve((size_t)NB * 4);        // |
    size_t zspan  = off;                                 // bytes to zero
    int*   rowptr = (int*)carve((size_t)(N + 1) * 4);
    float* dinv   = (float*)carve((size_t)N * 4);
    int2*  erec   = (int2*)carve((size_t)E * 8);
    float* a1     = (float*)carve((size_t)N * 128 * 4);
    int*   epos   = (int*)a1;   // alias: epos dead before a1 is first written

    if (off > ws_size) return;  // diagnostic guard

    // 1) CSR + packed edge records
    hipMemsetAsync(cnt, 0, zspan, stream);
    k_count<<<(E + 255) / 256, 256, 0, stream>>>(dst, cnt, epos, E);
    k_scan1<<<NB, 256, 0, stream>>>(cnt, rowptr, dinv, flg, incl, N, NB);
    k_fill <<<(E + 255) / 256, 256, 0, stream>>>(src, dst, rowptr, epos, dinv, erec, E);

    const int nblk = (N + RPB - 1) / RPB;
    // 2) layer 1: a1 = relu((M x) @ W1 + b1)
    fused_layer<128, 4, true><<<nblk, 256, 0, stream>>>(x, W1, b1, rowptr, erec, dinv, a1, N);
    // 3) layer 2: out = (M a1) @ W2 + b2
    fused_layer<64, 2, false><<<nblk, 256, 0, stream>>>(a1, W2, b2, rowptr, erec, dinv, out, N);
}

// Round 6
// 227.129 us; speedup vs baseline: 4.8283x; 1.1645x over previous
//
#include <hip/hip_runtime.h>
#include <math.h>

// ---------------------------------------------------------------------------
// 2-layer GCN, commuted form:  layer(X) = act((M·X)@W + b),  M = D^-1/2(A+I)D^-1/2
// Gather sources in bf16 (half the random-read bytes; fp32 accumulate+GEMM).
// Per-row register gather, 4-wide branch-free edge pipeline, fused into GEMM.
// CSR built per call: (convert|histogram) -> chained scan -> scatter.
// ---------------------------------------------------------------------------

#define SCAN_CHUNK 8192
#define RPB 32                      // node rows per fused block

__device__ __forceinline__ unsigned short f2bf(float f) {
    unsigned u = __float_as_uint(f);
    unsigned r = (u + 0x7fff + ((u >> 16) & 1)) >> 16;   // RTNE
    return (unsigned short)r;
}
__device__ __forceinline__ unsigned pk2(float a, float b) {
    return (unsigned)f2bf(a) | ((unsigned)f2bf(b) << 16);
}

// blocks [0,CB): convert x -> bf16 (8 elems/thread); blocks [CB,...): degree histogram
__global__ __launch_bounds__(256) void k_prep(const float* __restrict__ x,
                                              unsigned short* __restrict__ xh, int nElem,
                                              const int* __restrict__ dst, int* cnt,
                                              int* __restrict__ epos, int e, int CB) {
    if ((int)blockIdx.x < CB) {
        int i8 = (blockIdx.x * 256 + threadIdx.x) * 8;
        if (i8 < nElem) {
            float4 v0 = *(const float4*)&x[i8];
            float4 v1 = *(const float4*)&x[i8 + 4];
            uint4 o;
            o.x = pk2(v0.x, v0.y); o.y = pk2(v0.z, v0.w);
            o.z = pk2(v1.x, v1.y); o.w = pk2(v1.z, v1.w);
            *(uint4*)&xh[i8] = o;
        }
    } else {
        int i = (blockIdx.x - CB) * 256 + threadIdx.x;
        if (i < e) epos[i] = atomicAdd(&cnt[dst[i]], 1);
    }
}

// Single-kernel chained exclusive scan (nb blocks, 8192 elems each); emits dinv.
__global__ __launch_bounds__(256) void k_scan1(const int* __restrict__ cnt,
                                               int* __restrict__ rowptr, float* __restrict__ dinv,
                                               int* __restrict__ flg, int* __restrict__ incl,
                                               int n, int nb) {
    __shared__ int part[256];
    __shared__ int sPrev;
    const int t   = threadIdx.x;
    const int blk = blockIdx.x;
    const int base = blk * SCAN_CHUNK + t * 32;
    int v[32];
    int s = 0;
#pragma unroll
    for (int q = 0; q < 32; ++q) {
        int i = base + q;
        v[q] = (i < n) ? cnt[i] : 0;
        s += v[q];
    }
    part[t] = s;
    __syncthreads();
    for (int off = 1; off < 256; off <<= 1) {
        int u = (t >= off) ? part[t - off] : 0;
        __syncthreads();
        part[t] += u;
        __syncthreads();
    }
    if (t == 0) {
        int prev = 0;
        if (blk > 0) {
            while (__hip_atomic_load(&flg[blk - 1], __ATOMIC_ACQUIRE, __HIP_MEMORY_SCOPE_AGENT) == 0) {}
            prev = __hip_atomic_load(&incl[blk - 1], __ATOMIC_RELAXED, __HIP_MEMORY_SCOPE_AGENT);
        }
        const int total = part[255];
        __hip_atomic_store(&incl[blk], prev + total, __ATOMIC_RELAXED, __HIP_MEMORY_SCOPE_AGENT);
        __hip_atomic_store(&flg[blk], 1, __ATOMIC_RELEASE, __HIP_MEMORY_SCOPE_AGENT);
        if (blk == nb - 1) rowptr[n] = prev + total;
        sPrev = prev;
    }
    __syncthreads();
    int run = sPrev + part[t] - s;
#pragma unroll
    for (int q = 0; q < 32; ++q) {
        int i = base + q;
        if (i < n) {
            rowptr[i] = run;
            dinv[i]   = rsqrtf((float)(v[q] + 1));   // +1 self-loop
            run += v[q];
        }
    }
}

// Packed edge records sorted by dst: (src, dinv[src]*dinv[dst])
__global__ __launch_bounds__(256) void k_fill(const int* __restrict__ src, const int* __restrict__ dst,
                                              const int* __restrict__ rowptr, const int* __restrict__ epos,
                                              const float* __restrict__ dinv,
                                              int2* __restrict__ erec, int e) {
    int i = blockIdx.x * blockDim.x + threadIdx.x;
    if (i < e) {
        int d = dst[i];
        int s = src[i];
        erec[rowptr[d] + epos[i]] = make_int2(s, __float_as_int(dinv[s] * dinv[d]));
    }
}

// ---------------------------------------------------------------------------
// Fused layer: Out[r] = act((M·Xh)[r] @ W + bias), RPB=32 rows / 256-thr block.
// Gather: 8 lanes/row, 16 bf16 feats/lane (2x uint4 loads), 4 edges per iter
// (branch-free, coef=0 tail padding), next-iter record prefetch.
// GEMM: fp32, W staged in 32-k LDS chunks; TRx4 register tile per thread.
// OUTBF: epilogue stores bf16 (layer 1 -> a1) else fp32 (layer 2 -> d_out).
// ---------------------------------------------------------------------------
__device__ __forceinline__ void acc16(float* ga, float c, uint4 u0, uint4 u1) {
    ga[0]  += c * __uint_as_float(u0.x << 16);
    ga[1]  += c * __uint_as_float(u0.x & 0xffff0000u);
    ga[2]  += c * __uint_as_float(u0.y << 16);
    ga[3]  += c * __uint_as_float(u0.y & 0xffff0000u);
    ga[4]  += c * __uint_as_float(u0.z << 16);
    ga[5]  += c * __uint_as_float(u0.z & 0xffff0000u);
    ga[6]  += c * __uint_as_float(u0.w << 16);
    ga[7]  += c * __uint_as_float(u0.w & 0xffff0000u);
    ga[8]  += c * __uint_as_float(u1.x << 16);
    ga[9]  += c * __uint_as_float(u1.x & 0xffff0000u);
    ga[10] += c * __uint_as_float(u1.y << 16);
    ga[11] += c * __uint_as_float(u1.y & 0xffff0000u);
    ga[12] += c * __uint_as_float(u1.z << 16);
    ga[13] += c * __uint_as_float(u1.z & 0xffff0000u);
    ga[14] += c * __uint_as_float(u1.w << 16);
    ga[15] += c * __uint_as_float(u1.w & 0xffff0000u);
}

template <int COLS, int TR, bool RELU, bool OUTBF>
__global__ __launch_bounds__(256, 4) void fused_layer(const unsigned short* __restrict__ Xh,
                                                      const float* __restrict__ W,
                                                      const float* __restrict__ bias,
                                                      const int* __restrict__ rowptr,
                                                      const int2* __restrict__ erec,
                                                      const float* __restrict__ dinv,
                                                      void* __restrict__ OutP, int n) {
    constexpr int PAD = RPB + 4;                 // 36 floats (16B multiple)
    __shared__ __align__(16) float sM[128][PAD];
    __shared__ __align__(16) float sW[32][COLS];

    const int t     = threadIdx.x;
    const int row0  = blockIdx.x * RPB;
    const int r     = t >> 3;                    // row-in-block 0..31
    const int lane2 = (t & 7) * 2;               // uint4 index within 256B row
    const int seg   = (t & 7) * 16;              // feature base

    // ---- gather: ga[16] = dinv_d^2*Xh[d] + sum_e coef_e*Xh[src_e] ----
    {
        const int d = row0 + r;
        if (d < n) {
            float ga[16] = {};
            {
                const float wd = dinv[d];
                const uint4* P = (const uint4*)(Xh + ((size_t)d << 7)) + lane2;
                acc16(ga, wd * wd, P[0], P[1]);
            }
            const int beg = rowptr[d], end = rowptr[d + 1];
            int j = beg;
            const int2 Z = make_int2(0, 0);
            int2 r0 = (j     < end) ? erec[j]     : Z;
            int2 r1 = (j + 1 < end) ? erec[j + 1] : Z;
            int2 r2 = (j + 2 < end) ? erec[j + 2] : Z;
            int2 r3 = (j + 3 < end) ? erec[j + 3] : Z;
            while (j < end) {
                const int2 c0 = r0, c1 = r1, c2 = r2, c3 = r3;
                const int jn = j + 4;
                r0 = (jn     < end) ? erec[jn]     : Z;   // prefetch next quad
                r1 = (jn + 1 < end) ? erec[jn + 1] : Z;
                r2 = (jn + 2 < end) ? erec[jn + 2] : Z;
                r3 = (jn + 3 < end) ? erec[jn + 3] : Z;
                const uint4* P0 = (const uint4*)(Xh + ((size_t)c0.x << 7)) + lane2;
                const uint4* P1 = (const uint4*)(Xh + ((size_t)c1.x << 7)) + lane2;
                const uint4* P2 = (const uint4*)(Xh + ((size_t)c2.x << 7)) + lane2;
                const uint4* P3 = (const uint4*)(Xh + ((size_t)c3.x << 7)) + lane2;
                uint4 a0 = P0[0], a1 = P0[1];
                uint4 b0 = P1[0], b1 = P1[1];
                uint4 d0 = P2[0], d1 = P2[1];
                uint4 e0 = P3[0], e1 = P3[1];
                acc16(ga, __int_as_float(c0.y), a0, a1);  // coef 0 for tail slots
                acc16(ga, __int_as_float(c1.y), b0, b1);
                acc16(ga, __int_as_float(c2.y), d0, d1);
                acc16(ga, __int_as_float(c3.y), e0, e1);
                j = jn;
            }
#pragma unroll
            for (int q = 0; q < 16; ++q) sM[seg + q][r] = ga[q];
        } else {
#pragma unroll
            for (int q = 0; q < 16; ++q) sM[seg + q][r] = 0.f;
        }
    }

    // ---- GEMM: acc[TR][4] per thread ----
    const int tcx = t % (COLS / 4);
    const int tcy = t / (COLS / 4);
    float acc[TR][4] = {};

    for (int kc = 0; kc < 128; kc += 32) {
        __syncthreads();                          // 1st: sM ready; later: sW reuse safe
        const float4* Wf4 = (const float4*)(W + (size_t)kc * COLS);
        float4* sWf4 = (float4*)&sW[0][0];
        for (int f = t; f < 32 * COLS / 4; f += 256) sWf4[f] = Wf4[f];
        __syncthreads();
#pragma unroll 8
        for (int k = 0; k < 32; ++k) {
            float av[TR];
            if constexpr (TR == 4) {
                float4 a = *(const float4*)&sM[kc + k][tcy * 4];
                av[0] = a.x; av[1] = a.y; av[2] = a.z; av[3] = a.w;
            } else {
                float2 a = *(const float2*)&sM[kc + k][tcy * 2];
                av[0] = a.x; av[1] = a.y;
            }
            float4 b = *(const float4*)&sW[k][tcx * 4];
            float bv[4] = {b.x, b.y, b.z, b.w};
#pragma unroll
            for (int ii = 0; ii < TR; ++ii)
#pragma unroll
                for (int jj = 0; jj < 4; ++jj) acc[ii][jj] += av[ii] * bv[jj];
        }
    }

    // ---- epilogue ----
    float4 bv4 = *(const float4*)&bias[tcx * 4];
    float bb[4] = {bv4.x, bv4.y, bv4.z, bv4.w};
#pragma unroll
    for (int ii = 0; ii < TR; ++ii) {
        int rr = row0 + tcy * TR + ii;
        if (rr < n) {
            float o[4];
#pragma unroll
            for (int jj = 0; jj < 4; ++jj) {
                o[jj] = acc[ii][jj] + bb[jj];
                if (RELU) o[jj] = fmaxf(o[jj], 0.f);
            }
            if constexpr (OUTBF) {
                ushort4 ov;
                ov.x = f2bf(o[0]); ov.y = f2bf(o[1]); ov.z = f2bf(o[2]); ov.w = f2bf(o[3]);
                *(ushort4*)&((unsigned short*)OutP)[(size_t)rr * COLS + tcx * 4] = ov;
            } else {
                *(float4*)&((float*)OutP)[(size_t)rr * COLS + tcx * 4] =
                    make_float4(o[0], o[1], o[2], o[3]);
            }
        }
    }
}

// ---------------------------------------------------------------------------

extern "C" void kernel_launch(void* const* d_in, const int* in_sizes, int n_in,
                              void* d_out, int out_size, void* d_ws, size_t ws_size,
                              hipStream_t stream) {
    const float* x  = (const float*)d_in[0];
    const int*   ei = (const int*)d_in[1];
    const float* W1 = (const float*)d_in[2];
    const float* b1 = (const float*)d_in[3];
    const float* W2 = (const float*)d_in[4];
    const float* b2 = (const float*)d_in[5];
    float* out = (float*)d_out;

    const int N = in_sizes[0] / 128;
    const int E = in_sizes[1] / 2;
    const int* src = ei;
    const int* dst = ei + E;
    const int NB = (N + SCAN_CHUNK - 1) / SCAN_CHUNK;   // 7 for N=50000

    // workspace carve (256B aligned)
    size_t off = 0;
    char* base = (char*)d_ws;
    auto carve = [&](size_t bytes) -> void* {
        void* p = base + off;
        off += (bytes + 255) & ~(size_t)255;
        return p;
    };
    int*   cnt    = (int*)carve((size_t)N * 4);         // | zeroed as one span
    int*   flg    = (int*)carve((size_t)NB * 4);        // |
    int*   incl   = (int*)carve((size_t)NB * 4);        // |
    size_t zspan  = off;
    int*   rowptr = (int*)carve((size_t)(N + 1) * 4);
    float* dinv   = (float*)carve((size_t)N * 4);
    int2*  erec   = (int2*)carve((size_t)E * 8);
    unsigned short* xh = (unsigned short*)carve((size_t)N * 128 * 2);
    unsigned short* a1 = (unsigned short*)carve((size_t)N * 128 * 2);
    int*   epos   = (int*)a1;   // alias: epos dead before a1 is written (L1 epilogue)

    if (off > ws_size) return;  // diagnostic guard

    // 1) bf16 convert + degree histogram (one launch), chained scan, scatter
    const int nElem = N * 128;
    const int CB = (nElem / 8 + 255) / 256;
    const int EB = (E + 255) / 256;
    hipMemsetAsync(cnt, 0, zspan, stream);
    k_prep <<<CB + EB, 256, 0, stream>>>(x, xh, nElem, dst, cnt, epos, E, CB);
    k_scan1<<<NB, 256, 0, stream>>>(cnt, rowptr, dinv, flg, incl, N, NB);
    k_fill <<<EB, 256, 0, stream>>>(src, dst, rowptr, epos, dinv, erec, E);

    const int nblk = (N + RPB - 1) / RPB;
    // 2) layer 1: a1 = bf16(relu((M xh) @ W1 + b1))
    fused_layer<128, 4, true, true><<<nblk, 256, 0, stream>>>(
        xh, W1, b1, rowptr, erec, dinv, a1, N);
    // 3) layer 2: out = (M a1) @ W2 + b2   (fp32 out)
    fused_layer<64, 2, false, false><<<nblk, 256, 0, stream>>>(
        a1, W2, b2, rowptr, erec, dinv, out, N);
}